// Round 11
// baseline (1182.639 us; speedup 1.0000x reference)
//
#include <hip/hip_runtime.h>
#include <hip/hip_bf16.h>

// Problem constants
#define SEQ 50
#define DD  512
#define NHD 8
#define HDIM 64
#define MPROWS 38400   // 3*256*50  (rows per stream half)
#define MTROWS 76800   // 2*MPROWS

typedef __hip_bfloat16 bf;
typedef __attribute__((ext_vector_type(8))) short bf16x8;
typedef __attribute__((ext_vector_type(4))) float f32x4;

__device__ __forceinline__ float bf2f(unsigned short u) {
    unsigned int x = ((unsigned int)u) << 16;
    return __builtin_bit_cast(float, x);
}
__device__ __forceinline__ unsigned short f2bu(float f) {
    unsigned int u = __builtin_bit_cast(unsigned int, f);
    u += 0x7fffu + ((u >> 16) & 1u);
    return (unsigned short)(u >> 16);
}

#define ASYNC16(g, l) __builtin_amdgcn_global_load_lds( \
    (__attribute__((address_space(1))) void*)(g),       \
    (__attribute__((address_space(3))) void*)(l), 16, 0, 0)

// ---------------------------------------------------------------------------
__global__ __launch_bounds__(256) void transpose_cast(
    const float* __restrict__ src, bf* __restrict__ dst,
    int R, int C, size_t sStride, size_t dStride)
{
    __shared__ float tile[32][33];
    int l = blockIdx.z;
    src += (size_t)l * sStride;
    dst += (size_t)l * dStride;
    int c0 = blockIdx.x * 32, r0 = blockIdx.y * 32;
    int tx = threadIdx.x & 31, ty = threadIdx.x >> 5;
    for (int i = ty; i < 32; i += 8)
        tile[i][tx] = src[(size_t)(r0 + i) * C + c0 + tx];
    __syncthreads();
    for (int i = ty; i < 32; i += 8)
        dst[(size_t)(c0 + i) * R + r0 + tx] = __float2bfloat16(tile[tx][i]);
}

__global__ __launch_bounds__(256) void biascat_kernel(
    const float* __restrict__ bq, const float* __restrict__ bk,
    const float* __restrict__ bv, float* __restrict__ out)
{
    int i = blockIdx.x * 256 + threadIdx.x;
    if (i >= 4 * 1536) return;
    int l = i / 1536, c = i % 1536;
    float v;
    if (c < 512)       v = bq[l * 512 + c];
    else if (c < 1024) v = bk[l * 512 + c - 512];
    else               v = bv[l * 512 + c - 1024];
    out[i] = v;
}

__global__ __launch_bounds__(256) void tproj_kernel(
    const float* __restrict__ types_tab, const bf* __restrict__ WTqkv,
    bf* __restrict__ Tt)
{
    int gid = blockIdx.x * 256 + threadIdx.x;
    if (gid >= 9216) return;
    int hl = gid / 4608;
    int t  = (gid / 1536) % 3;
    int n  = gid % 1536;
    const unsigned short* w =
        (const unsigned short*)(WTqkv + (size_t)(hl * 2) * 786432 + (size_t)n * 512);
    const float* ty = types_tab + t * 512;
    float a = 0.f;
    for (int k = 0; k < 512; ++k) a += ty[k] * bf2f(w[k]);
    Tt[gid] = __float2bfloat16(a);
}

// ---------------------------------------------------------------------------
__global__ __launch_bounds__(256) void embed_kernel(
    const int* __restrict__ probs_his, const int* __restrict__ knows_his,
    const int* __restrict__ corrs, const float* __restrict__ knows_tab,
    const float* __restrict__ probs_tab, const float* __restrict__ types_tab,
    const float* __restrict__ pos_tab, bf* __restrict__ info, bf* __restrict__ X)
{
    int bs = blockIdx.x * 4 + (threadIdx.x >> 6);
    int lane = threadIdx.x & 63;
    int s = bs % SEQ;
    int p = probs_his[bs];
    int c = corrs[bs];
    int d0 = lane * 8;

    float v[8];
    #pragma unroll
    for (int j = 0; j < 8; ++j)
        v[j] = probs_tab[(size_t)p * DD + d0 + j] + pos_tab[(size_t)s * DD + d0 + j];
    for (int k = 0; k < 8; ++k) {
        int ki = knows_his[bs * 8 + k];
        const float* kr = knows_tab + (size_t)ki * DD + d0;
        #pragma unroll
        for (int j = 0; j < 8; ++j) v[j] += kr[j];
    }
    int t0 = c ? 1 : 2;
    int t1 = c ? 2 : 0;
    int t2 = c ? 1 : 0;
    const float* T0 = types_tab + t0 * DD + d0;
    const float* T1 = types_tab + t1 * DD + d0;
    const float* T2 = types_tab + t2 * DD + d0;
    uint4 xi, x0, x1, x2;
    unsigned short* pi = (unsigned short*)&xi;
    unsigned short* p0 = (unsigned short*)&x0;
    unsigned short* p1 = (unsigned short*)&x1;
    unsigned short* p2 = (unsigned short*)&x2;
    #pragma unroll
    for (int j = 0; j < 8; ++j) {
        pi[j] = f2bu(v[j]);
        p0[j] = f2bu(v[j] + T0[j]);
        p1[j] = f2bu(v[j] + T1[j]);
        p2[j] = f2bu(v[j] + T2[j]);
    }
    size_t base = (size_t)bs * DD + d0;
    const size_t PB = (size_t)12800 * DD;
    *(uint4*)(info + base) = xi;
    *(uint4*)(X + 0 * PB + base) = x0;
    *(uint4*)(X + 1 * PB + base) = x1;
    *(uint4*)(X + 2 * PB + base) = x2;
    *(uint4*)(X + 3 * PB + base) = x0;
    *(uint4*)(X + 4 * PB + base) = x1;
    *(uint4*)(X + 5 * PB + base) = x2;
}

// ---------------------------------------------------------------------------
// GEMM 128x128 (proven core, round-7 scalar epilogue). Used for head path
// and fallback.
template <int RELU>
__global__ __launch_bounds__(256) void gemm_bt(
    const bf* __restrict__ Ap, const bf* __restrict__ WT0, const bf* __restrict__ WT1,
    const float* __restrict__ bias0, const float* __restrict__ bias1,
    bf* __restrict__ Cp, int N, int Kd, int nN, int mtHalf)
{
    __shared__ bf Al[128 * 64];
    __shared__ bf Bl[128 * 64];
    int nwg = gridDim.x;
    int f = blockIdx.x;
    int q8 = nwg >> 3, r8 = nwg & 7;
    int xcd = f & 7, pos = f >> 3;
    int e = (xcd < r8 ? xcd * (q8 + 1) : r8 * (q8 + 1) + (xcd - r8) * q8) + pos;
    int bm = e / nN, bn = e - bm * nN;
    const bf* WTp;
    const float* bias;
    if (bm < mtHalf) { WTp = WT0; bias = bias0; }
    else             { WTp = WT1; bias = bias1; }
    int m0 = bm * 128, n0 = bn * 128;
    int t = threadIdx.x, lane = t & 63, wave = t >> 6;
    int wr = wave >> 1, wc = wave & 1;
    int lr = lane & 15, lg = lane >> 4;

    f32x4 acc[4][4];
    #pragma unroll
    for (int m = 0; m < 4; ++m)
        #pragma unroll
        for (int n = 0; n < 4; ++n)
            acc[m][n] = (f32x4){0.f, 0.f, 0.f, 0.f};

    for (int kt = 0; kt < Kd; kt += 64) {
        #pragma unroll
        for (int i = 0; i < 4; ++i) {
            int c = i * 256 + t;
            int row = c >> 3, col = (c & 7) * 8;
            ASYNC16(Ap  + (size_t)(m0 + row) * Kd + kt + col, Al + c * 8);
            ASYNC16(WTp + (size_t)(n0 + row) * Kd + kt + col, Bl + c * 8);
        }
        __syncthreads();
        #pragma unroll
        for (int kk = 0; kk < 64; kk += 32) {
            int ko = kk + lg * 8;
            bf16x8 af[4], bfr[4];
            #pragma unroll
            for (int m = 0; m < 4; ++m)
                af[m] = *(const bf16x8*)(Al + (wr * 64 + m * 16 + lr) * 64 + ko);
            #pragma unroll
            for (int n = 0; n < 4; ++n)
                bfr[n] = *(const bf16x8*)(Bl + (wc * 64 + n * 16 + lr) * 64 + ko);
            #pragma unroll
            for (int m = 0; m < 4; ++m)
                #pragma unroll
                for (int n = 0; n < 4; ++n)
                    acc[m][n] = __builtin_amdgcn_mfma_f32_16x16x32_bf16(af[m], bfr[n], acc[m][n], 0, 0, 0);
        }
        __syncthreads();
    }
    unsigned short* Cs = (unsigned short*)Cp;
    #pragma unroll
    for (int n = 0; n < 4; ++n) {
        int col = n0 + wc * 64 + n * 16 + lr;
        float bvv = bias[col];
        #pragma unroll
        for (int m = 0; m < 4; ++m) {
            #pragma unroll
            for (int r = 0; r < 4; ++r) {
                int row = m0 + wr * 64 + m * 16 + lg * 4 + r;
                float v = acc[m][n][r] + bvv;
                if (RELU) v = fmaxf(v, 0.f);
                Cs[(size_t)row * N + col] = f2bu(v);
            }
        }
    }
}

// ---------------------------------------------------------------------------
// 256x256 8-phase GEMM (proven round-10 core) + two-weight select +
// LDS-repacked vectorized epilogue (As/Bs = exactly one 256x256 bf16 tile).
template <int RELU>
__global__ __launch_bounds__(512, 2) void gemm8(
    const bf* __restrict__ Ap, const bf* __restrict__ WT0, const bf* __restrict__ WT1,
    const float* __restrict__ bias0, const float* __restrict__ bias1,
    bf* __restrict__ Cp, int N, int Kd, int nN, int mtHalf)
{
    __shared__ __align__(16) bf As[2][16384];
    __shared__ __align__(16) bf Bs[2][16384];

    int nwg = gridDim.x, f = blockIdx.x;
    int q8 = nwg >> 3, r8 = nwg & 7;
    int xcd = f & 7, pos = f >> 3;
    int e = (xcd < r8 ? xcd * (q8 + 1) : r8 * (q8 + 1) + (xcd - r8) * q8) + pos;
    int bm = e / nN, bn = e - bm * nN;
    const bf* WTp;
    const float* bias;
    if (bm < mtHalf) { WTp = WT0; bias = bias0; }
    else             { WTp = WT1; bias = bias1; }
    int m0 = bm * 256, n0 = bn * 256;
    int t = threadIdx.x, lane = t & 63, wave = t >> 6;
    int wm = wave >> 2, wn = wave & 3;
    int lr = lane & 15, kg = lane >> 4;

    int srow = t >> 3;          // 0..63 (row within 64-row load group)
    int scolb = (t & 7) * 16;   // dest col byte (linear)
    const bf* Abase = Ap + (size_t)m0 * Kd;
    const bf* Bbase = WTp + (size_t)n0 * Kd;

#define STG(dsts, base, half, kt) do {                                        \
    _Pragma("unroll")                                                         \
    for (int _i = 0; _i < 2; ++_i) {                                          \
        int _r = (half) * 128 + _i * 64 + srow;                               \
        ASYNC16((base) + (size_t)_r * Kd + (kt) +                             \
                    ((scolb ^ ((_r & 7) << 4)) >> 1),                         \
                (dsts) + _r * 64 + (t & 7) * 8);                              \
    } } while (0)

    f32x4 acc[8][4];
    #pragma unroll
    for (int m = 0; m < 8; ++m)
        #pragma unroll
        for (int n = 0; n < 4; ++n)
            acc[m][n] = (f32x4){0.f, 0.f, 0.f, 0.f};

    STG(As[0], Abase, 0, 0);
    STG(As[0], Abase, 1, 0);
    STG(Bs[0], Bbase, 0, 0);
    STG(Bs[0], Bbase, 1, 0);

    int ntile = Kd >> 6;
    bf16x8 breg[4][2];
    for (int j = 0; j < ntile; ++j) {
        int d = j & 1;
        const char* Ab = (const char*)As[d];
        const char* Bb = (const char*)Bs[d];
        asm volatile("s_waitcnt vmcnt(0)" ::: "memory");
        __builtin_amdgcn_s_barrier();
        int kt1 = (j + 1) << 6;
        int pf = (j + 1 < ntile);
        #pragma unroll
        for (int q = 0; q < 4; ++q) {
            if (q == 0) {
                #pragma unroll
                for (int ns = 0; ns < 4; ++ns) {
                    int row = wn * 64 + ns * 16 + lr;
                    int sw = (row & 7) << 4;
                    breg[ns][0] = *(const bf16x8*)(Bb + row * 128 + ((kg * 16) ^ sw));
                    breg[ns][1] = *(const bf16x8*)(Bb + row * 128 + ((64 + kg * 16) ^ sw));
                }
            }
            bf16x8 areg[2][2];
            #pragma unroll
            for (int mm = 0; mm < 2; ++mm) {
                int row = wm * 128 + (2 * q + mm) * 16 + lr;
                int sw = (row & 7) << 4;
                areg[mm][0] = *(const bf16x8*)(Ab + row * 128 + ((kg * 16) ^ sw));
                areg[mm][1] = *(const bf16x8*)(Ab + row * 128 + ((64 + kg * 16) ^ sw));
            }
            if (pf) {
                if (q == 0)      STG(As[d ^ 1], Abase, 0, kt1);
                else if (q == 1) STG(As[d ^ 1], Abase, 1, kt1);
                else if (q == 2) STG(Bs[d ^ 1], Bbase, 0, kt1);
                else             STG(Bs[d ^ 1], Bbase, 1, kt1);
            }
            __builtin_amdgcn_s_barrier();
            __builtin_amdgcn_s_setprio(1);
            #pragma unroll
            for (int mm = 0; mm < 2; ++mm)
                #pragma unroll
                for (int ns = 0; ns < 4; ++ns) {
                    acc[2 * q + mm][ns] = __builtin_amdgcn_mfma_f32_16x16x32_bf16(
                        areg[mm][0], breg[ns][0], acc[2 * q + mm][ns], 0, 0, 0);
                    acc[2 * q + mm][ns] = __builtin_amdgcn_mfma_f32_16x16x32_bf16(
                        areg[mm][1], breg[ns][1], acc[2 * q + mm][ns], 0, 0, 0);
                }
            __builtin_amdgcn_s_setprio(0);
            if (q != 3) __builtin_amdgcn_s_barrier();
        }
    }
#undef STG

    // ---- epilogue: repack 256x256 bf16 tile through As(rows 0-127)/Bs(128-255)
    __syncthreads();
    {
        char* base = (wm == 0) ? (char*)&As[0][0] : (char*)&Bs[0][0];
        #pragma unroll
        for (int ns = 0; ns < 4; ++ns) {
            int col = wn * 64 + ns * 16 + lr;          // tile col 0..255
            float bvv = bias[n0 + col];
            #pragma unroll
            for (int ms = 0; ms < 8; ++ms) {
                #pragma unroll
                for (int rr = 0; rr < 4; ++rr) {
                    int r128 = ms * 16 + kg * 4 + rr;  // row within half
                    float v = acc[ms][ns][rr] + bvv;
                    if (RELU) v = fmaxf(v, 0.f);
                    *(unsigned short*)(base + r128 * 512 +
                        ((col * 2) ^ ((r128 & 7) << 4))) = f2bu(v);
                }
            }
        }
    }
    __syncthreads();
    {
        unsigned short* Cs = (unsigned short*)Cp;
        int row = t >> 1, hb = (t & 1) * 256;
        int r128 = row & 127;
        const char* src = (row < 128) ? (const char*)&As[0][0] : (const char*)&Bs[0][0];
        char* Crow = (char*)(Cs + (size_t)(m0 + row) * N + n0);
        int sw = (r128 & 7) << 4;
        #pragma unroll
        for (int i2 = 0; i2 < 16; ++i2) {
            int cb = hb + i2 * 16;
            uint4 v = *(const uint4*)(src + r128 * 512 + (cb ^ sw));
            *(uint4*)(Crow + cb) = v;
        }
    }
}

// ---------------------------------------------------------------------------
// Head GEMM (round-7 proven): h1 = relu(Hin @ pW1a + IP[row%12800]).
__global__ __launch_bounds__(256) void gemm_head(
    const bf* __restrict__ Ap, const bf* __restrict__ WTp,
    const bf* __restrict__ IPp, bf* __restrict__ Cp, int nN)
{
    __shared__ bf Al[128 * 64];
    __shared__ bf Bl[128 * 64];
    const int Kd = 512, N = 512;
    int nwg = gridDim.x;
    int f = blockIdx.x;
    int q8 = nwg >> 3, r8 = nwg & 7;
    int xcd = f & 7, pos = f >> 3;
    int e = (xcd < r8 ? xcd * (q8 + 1) : r8 * (q8 + 1) + (xcd - r8) * q8) + pos;
    int bm = e / nN, bn = e - bm * nN;
    int m0 = bm * 128, n0 = bn * 128;
    int t = threadIdx.x, lane = t & 63, wave = t >> 6;
    int wr = wave >> 1, wc = wave & 1;
    int lr = lane & 15, lg = lane >> 4;

    f32x4 acc[4][4];
    #pragma unroll
    for (int m = 0; m < 4; ++m)
        #pragma unroll
        for (int n = 0; n < 4; ++n)
            acc[m][n] = (f32x4){0.f, 0.f, 0.f, 0.f};

    for (int kt = 0; kt < Kd; kt += 64) {
        #pragma unroll
        for (int i = 0; i < 4; ++i) {
            int c = i * 256 + t;
            int row = c >> 3, col = (c & 7) * 8;
            ASYNC16(Ap  + (size_t)(m0 + row) * Kd + kt + col, Al + c * 8);
            ASYNC16(WTp + (size_t)(n0 + row) * Kd + kt + col, Bl + c * 8);
        }
        __syncthreads();
        #pragma unroll
        for (int kk = 0; kk < 64; kk += 32) {
            int ko = kk + lg * 8;
            bf16x8 af[4], bfr[4];
            #pragma unroll
            for (int m = 0; m < 4; ++m)
                af[m] = *(const bf16x8*)(Al + (wr * 64 + m * 16 + lr) * 64 + ko);
            #pragma unroll
            for (int n = 0; n < 4; ++n)
                bfr[n] = *(const bf16x8*)(Bl + (wc * 64 + n * 16 + lr) * 64 + ko);
            #pragma unroll
            for (int m = 0; m < 4; ++m)
                #pragma unroll
                for (int n = 0; n < 4; ++n)
                    acc[m][n] = __builtin_amdgcn_mfma_f32_16x16x32_bf16(af[m], bfr[n], acc[m][n], 0, 0, 0);
        }
        __syncthreads();
    }
    unsigned short* Cs = (unsigned short*)Cp;
    const unsigned short* IPu = (const unsigned short*)IPp;
    #pragma unroll
    for (int n = 0; n < 4; ++n) {
        int col = n0 + wc * 64 + n * 16 + lr;
        #pragma unroll
        for (int m = 0; m < 4; ++m) {
            #pragma unroll
            for (int r = 0; r < 4; ++r) {
                int row = m0 + wr * 64 + m * 16 + lg * 4 + r;
                int rr = row % 12800;
                float v = acc[m][n][r] + bf2f(IPu[(size_t)rr * 512 + col]);
                v = fmaxf(v, 0.f);
                Cs[(size_t)row * N + col] = f2bu(v);
            }
        }
    }
}

// ---------------------------------------------------------------------------
// MFMA attention. One wave per (seq, head); 2 waves/block.
// L0=1: QKVc is the 12800-row base projection; per-row type projection
// Tsel[t(pass,corrs)] is added to Q/K fragments and V staging on the fly.
template <int L0>
__global__ __launch_bounds__(128, 2) void attn_mfma(
    const bf* __restrict__ QKVc, const int* __restrict__ probs_his,
    bf* __restrict__ Oc, int seq0,
    const bf* __restrict__ Tsel, const int* __restrict__ corrs)
{
    __shared__ bf Pl_s[2][4096];
    __shared__ bf Vt_s[2][4096];
    int wave = threadIdx.x >> 6, lane = threadIdx.x & 63;
    bf* Pl = Pl_s[wave];
    bf* Vt = Vt_s[wave];
    int task = blockIdx.x * 2 + wave;
    int h = task & 7, seqL = task >> 3;
    int seqG = seq0 + seqL;
    int st = seqG / 768, b = seqG % 256;
    int pass = (seqG % 768) / 256;       // 0=right,1=wrong,2=norm
    int lr = lane & 15, kg = lane >> 4;
    size_t qkrow = L0 ? (size_t)b * SEQ : (size_t)seqL * SEQ;
    const bf* Qb = QKVc + qkrow * 1536 + h * HDIM;
    const bf* Kb = Qb + 512;
    const bf* Vb = Qb + 1024;
    const unsigned short* Tu = (const unsigned short*)Tsel;

    int pvv = (lane < SEQ) ? probs_his[b * SEQ + lane] : 1;
    unsigned long long padm = __ballot(pvv == 0) | 0xFFFC000000000000ull;

    // ---- stage V transposed (swizzled); L0 adds Tv per key row
    #pragma unroll
    for (int it = 0; it < 8; ++it) {
        int idx = it * 64 + lane;
        int key = idx >> 3, d0 = (idx & 7) * 8;
        uint4 v4 = make_uint4(0u, 0u, 0u, 0u);
        if (key < SEQ) v4 = *(const uint4*)(Vb + (size_t)key * 1536 + d0);
        unsigned short* vs = (unsigned short*)&v4;
        if (L0) {
            int kk2 = (key < SEQ) ? key : (SEQ - 1);
            int cc = corrs[b * SEQ + kk2];
            int tt = (pass == 0) ? (cc ? 1 : 2) : (pass == 1) ? (cc ? 2 : 0) : (cc ? 1 : 0);
            const unsigned short* Tv = Tu + tt * 1536 + 1024 + h * HDIM + d0;
            #pragma unroll
            for (int j = 0; j < 8; ++j)
                vs[j] = f2bu(bf2f(vs[j]) + bf2f(Tv[j]));
        }
        #pragma unroll
        for (int j = 0; j < 8; ++j) {
            int d = d0 + j;
            int byt = (d * 128 + key * 2) ^ ((j & 7) << 4);
            *(unsigned short*)((char*)Vt + byt) = vs[j];
        }
    }

    // ---- S^T = K @ Q^T (L0 adds Tq/Tk per row)
    bf16x8 kf[4][2], qf[4][2];
    #pragma unroll
    for (int m = 0; m < 4; ++m) {
        int rk = 16 * m + lr; if (rk > SEQ - 1) rk = SEQ - 1;
        int tt = 0;
        if (L0) {
            int cc = corrs[b * SEQ + rk];
            tt = (pass == 0) ? (cc ? 1 : 2) : (pass == 1) ? (cc ? 2 : 0) : (cc ? 1 : 0);
        }
        #pragma unroll
        for (int kb = 0; kb < 2; ++kb) {
            kf[m][kb] = *(const bf16x8*)(Kb + (size_t)rk * 1536 + kb * 32 + kg * 8);
            qf[m][kb] = *(const bf16x8*)(Qb + (size_t)rk * 1536 + kb * 32 + kg * 8);
            if (L0) {
                const unsigned short* Tq = Tu + tt * 1536 + h * HDIM + kb * 32 + kg * 8;
                #pragma unroll
                for (int j = 0; j < 8; ++j) {
                    qf[m][kb][j] = (short)f2bu(bf2f((unsigned short)qf[m][kb][j]) + bf2f(Tq[j]));
                    kf[m][kb][j] = (short)f2bu(bf2f((unsigned short)kf[m][kb][j]) + bf2f(Tq[512 + j]));
                }
            }
        }
    }
    f32x4 sacc[4][4];
    #pragma unroll
    for (int m = 0; m < 4; ++m)
        #pragma unroll
        for (int n = 0; n < 4; ++n)
            sacc[m][n] = (f32x4){0.f, 0.f, 0.f, 0.f};
    #pragma unroll
    for (int kb = 0; kb < 2; ++kb)
        #pragma unroll
        for (int m = 0; m < 4; ++m)
            #pragma unroll
            for (int n = 0; n < 4; ++n)
                sacc[m][n] = __builtin_amdgcn_mfma_f32_16x16x32_bf16(kf[m][kb], qf[n][kb], sacc[m][n], 0, 0, 0);

    #pragma unroll
    for (int n = 0; n < 4; ++n) {
        int q = 16 * n + lr;
        int qpad = (int)((padm >> q) & 1ull);
        float p[4][4];
        float mx = -3e38f;
        #pragma unroll
        for (int m = 0; m < 4; ++m)
            #pragma unroll
            for (int r = 0; r < 4; ++r) {
                int key = 16 * m + 4 * kg + r;
                int blocked = qpad | (int)((padm >> key) & 1ull) |
                              (st == 0 ? (key > q) : (key < q));
                float s = sacc[m][n][r] * 0.125f;
                p[m][r] = blocked ? -3e38f : s;
                if (!blocked) mx = fmaxf(mx, s);
            }
        mx = fmaxf(mx, __shfl_xor(mx, 16));
        mx = fmaxf(mx, __shfl_xor(mx, 32));
        float sum = 0.f;
        #pragma unroll
        for (int m = 0; m < 4; ++m)
            #pragma unroll
            for (int r = 0; r < 4; ++r) {
                float e = (p[m][r] > -1e37f) ? __expf(p[m][r] - mx) : 0.f;
                p[m][r] = e;
                sum += e;
            }
        sum += __shfl_xor(sum, 16);
        sum += __shfl_xor(sum, 32);
        float inv = (sum > 0.f) ? 1.f / sum : 0.f;
        #pragma unroll
        for (int m = 0; m < 4; ++m) {
            unsigned int u0 = (unsigned int)f2bu(p[m][0] * inv) |
                              ((unsigned int)f2bu(p[m][1] * inv) << 16);
            unsigned int u1 = (unsigned int)f2bu(p[m][2] * inv) |
                              ((unsigned int)f2bu(p[m][3] * inv) << 16);
            int base = (q * 128 + (16 * m + 4 * kg) * 2) ^ ((q & 7) << 4);
            *(unsigned int*)((char*)Pl + base) = u0;
            *(unsigned int*)((char*)Pl + base + 4) = u1;
        }
    }

    f32x4 oacc[4][4];
    #pragma unroll
    for (int m = 0; m < 4; ++m)
        #pragma unroll
        for (int n = 0; n < 4; ++n)
            oacc[m][n] = (f32x4){0.f, 0.f, 0.f, 0.f};
    #pragma unroll
    for (int kb = 0; kb < 2; ++kb) {
        bf16x8 vf[4], pf[4];
        #pragma unroll
        for (int m = 0; m < 4; ++m) {
            int row = 16 * m + lr;
            int byt = (row * 128 + (kb * 32 + kg * 8) * 2) ^ ((row & 7) << 4);
            vf[m] = *(const bf16x8*)((char*)Vt + byt);
            pf[m] = *(const bf16x8*)((char*)Pl + byt);
        }
        #pragma unroll
        for (int m = 0; m < 4; ++m)
            #pragma unroll
            for (int n = 0; n < 4; ++n)
                oacc[m][n] = __builtin_amdgcn_mfma_f32_16x16x32_bf16(vf[m], pf[n], oacc[m][n], 0, 0, 0);
    }
    #pragma unroll
    for (int n = 0; n < 4; ++n) {
        int q = 16 * n + lr;
        if (q < SEQ) {
            #pragma unroll
            for (int m = 0; m < 4; ++m) {
                uint2 ov;
                ov.x = (unsigned int)f2bu(oacc[m][n][0]) | ((unsigned int)f2bu(oacc[m][n][1]) << 16);
                ov.y = (unsigned int)f2bu(oacc[m][n][2]) | ((unsigned int)f2bu(oacc[m][n][3]) << 16);
                *(uint2*)(Oc + (size_t)(seqL * SEQ + q) * DD + h * HDIM + 16 * m + 4 * kg) = ov;
            }
        }
    }
}

// ---------------------------------------------------------------------------
__global__ __launch_bounds__(256) void ln_kernel(
    bf* __restrict__ X, const bf* __restrict__ Rb,
    const float* __restrict__ g_all, const float* __restrict__ be_all,
    int lf, int lb)
{
    int row = blockIdx.x * 4 + (threadIdx.x >> 6);
    int lane = threadIdx.x & 63;
    int layer = (row < MPROWS) ? lf : lb;
    const float* g = g_all + layer * DD;
    const float* be = be_all + layer * DD;
    uint4 xa = *((const uint4*)(X + (size_t)row * DD) + lane);
    uint4 ra = *((const uint4*)(Rb + (size_t)row * DD) + lane);
    unsigned short* xs = (unsigned short*)&xa;
    unsigned short* rs = (unsigned short*)&ra;
    float v[8];
    float sum = 0.f;
    #pragma unroll
    for (int j = 0; j < 8; ++j) { v[j] = bf2f(xs[j]) + bf2f(rs[j]); sum += v[j]; }
    #pragma unroll
    for (int o = 1; o < 64; o <<= 1) sum += __shfl_xor(sum, o);
    float mu = sum * (1.f / 512.f);
    float ss = 0.f;
    #pragma unroll
    for (int j = 0; j < 8; ++j) { float d = v[j] - mu; ss += d * d; }
    #pragma unroll
    for (int o = 1; o < 64; o <<= 1) ss += __shfl_xor(ss, o);
    float inv = rsqrtf(ss * (1.f / 512.f) + 1e-5f);
    int d0 = lane * 8;
    uint4 ov;
    unsigned short* os = (unsigned short*)&ov;
    #pragma unroll
    for (int j = 0; j < 8; ++j)
        os[j] = f2bu((v[j] - mu) * inv * g[d0 + j] + be[d0 + j]);
    *((uint4*)(X + (size_t)row * DD) + lane) = ov;
}

// ---------------------------------------------------------------------------
__global__ __launch_bounds__(256) void combine_kernel(
    const bf* __restrict__ X, const bf* __restrict__ info,
    bf* __restrict__ Hinc, int rh0, int hstride, int withInfo)
{
    int rl = blockIdx.x * 4 + (threadIdx.x >> 6);
    int rh = rh0 + rl;
    int lane = threadIdx.x & 63;
    int s = rh % SEQ, pb = rh / SEQ, b = pb & 255;
    const size_t MPD = (size_t)MPROWS * DD;
    uint4 o;
    if (s == 0) {
        o = *((const uint4*)(X + MPD + (size_t)(pb * SEQ) * DD) + lane);
    } else if (s == SEQ - 1) {
        o = *((const uint4*)(X + (size_t)(pb * SEQ + SEQ - 1) * DD) + lane);
    } else {
        uint4 a = *((const uint4*)(X + (size_t)(pb * SEQ + s - 1) * DD) + lane);
        uint4 c2 = *((const uint4*)(X + MPD + (size_t)(pb * SEQ + s + 1) * DD) + lane);
        unsigned short* as = (unsigned short*)&a;
        unsigned short* cs = (unsigned short*)&c2;
        unsigned short* os = (unsigned short*)&o;
        #pragma unroll
        for (int j = 0; j < 8; ++j) os[j] = f2bu(bf2f(as[j]) + bf2f(cs[j]));
    }
    *((uint4*)(Hinc + (size_t)rl * hstride) + lane) = o;
    if (withInfo) {
        uint4 iv = *((const uint4*)(info + (size_t)(b * SEQ + s) * DD) + lane);
        *((uint4*)(Hinc + (size_t)rl * hstride + 512) + lane) = iv;
    }
}

// ---------------------------------------------------------------------------
__global__ __launch_bounds__(256) void head_final(
    const bf* __restrict__ h2c, const float* __restrict__ pW3,
    const float* __restrict__ pb3, const int* __restrict__ probs_his,
    float* __restrict__ out, int rh0)
{
    int rl = blockIdx.x * 4 + (threadIdx.x >> 6);
    int row = rh0 + rl;
    int lane = threadIdx.x & 63;
    uint2 hv = *((const uint2*)(h2c + (size_t)rl * 256) + lane);
    unsigned short* hs = (unsigned short*)&hv;
    float s = 0.f;
    #pragma unroll
    for (int j = 0; j < 4; ++j) s += bf2f(hs[j]) * pW3[lane * 4 + j];
    #pragma unroll
    for (int o = 1; o < 64; o <<= 1) s += __shfl_xor(s, o);
    if (lane == 0) {
        float logit = s + pb3[0];
        float sc = 1.f / (1.f + __expf(-logit));
        int bb = (row / SEQ) & 255, ss2 = row % SEQ;
        out[row] = (probs_his[bb * SEQ + ss2] > 0) ? sc : 0.f;
    }
}

// ---------------------------------------------------------------------------
extern "C" void kernel_launch(void* const* d_in, const int* in_sizes, int n_in,
                              void* d_out, int out_size, void* d_ws, size_t ws_size,
                              hipStream_t stream) {
    const int*   probs_his = (const int*)d_in[0];
    const int*   knows_his = (const int*)d_in[1];
    const int*   corrs     = (const int*)d_in[2];
    const float* knows_tab = (const float*)d_in[3];
    const float* probs_tab = (const float*)d_in[4];
    const float* types_tab = (const float*)d_in[5];
    const float* pos_tab   = (const float*)d_in[6];
    const float* Wq = (const float*)d_in[7];
    const float* Wk = (const float*)d_in[8];
    const float* Wv = (const float*)d_in[9];
    const float* W1 = (const float*)d_in[10];
    const float* W2 = (const float*)d_in[11];
    const float* bq = (const float*)d_in[12];
    const float* bk = (const float*)d_in[13];
    const float* bv = (const float*)d_in[14];
    const float* b1 = (const float*)d_in[15];
    const float* b2 = (const float*)d_in[16];
    const float* be1 = (const float*)d_in[17];
    const float* be2 = (const float*)d_in[18];
    const float* g1 = (const float*)d_in[19];
    const float* g2 = (const float*)d_in[20];
    const float* pW1 = (const float*)d_in[21];
    const float* pb1 = (const float*)d_in[22];
    const float* pW2 = (const float*)d_in[23];
    const float* pb2 = (const float*)d_in[24];
    const float* pW3 = (const float*)d_in[25];
    const float* pb3 = (const float*)d_in[26];

    char* ws = (char*)d_ws;
    bf* WTqkv = (bf*)(ws + 0);              // [4][1536][512]
    bf* WT1   = (bf*)(ws + 6291456);        // [4][512][512]
    bf* WT2   = (bf*)(ws + 8388608);        // [4][512][512]
    bf* pW1T  = (bf*)(ws + 10485760);       // [512][1024]   (fallback)
    bf* pW1aT = (bf*)(ws + 11534336);       // [512][512]
    bf* pW1bT = (bf*)(ws + 12058624);       // [512][512]
    bf* pW2T  = (bf*)(ws + 12582912);       // [256][512]
    float* bqkv = (float*)(ws + 12845056);  // [4][1536]
    bf* info  = (bf*)(ws + 12869632);       // [12800][512]
    bf* X     = (bf*)(ws + 25976832);       // [76800][512]
    const size_t FIXED = 104620032ull;      // X end
    const size_t FULLSCR = (size_t)38400 * 4096;

    int CR;
    if      (ws_size >= FIXED + FULLSCR)                  CR = 38400;
    else if (ws_size >= FIXED + (size_t)19200 * 4096)     CR = 19200;
    else if (ws_size >= FIXED + (size_t)9600  * 4096)     CR = 9600;
    else                                                  CR = 3200;
    const int full = (CR == 38400) &&
        (ws_size >= FIXED + FULLSCR + 18432);
    bf* Tt = (bf*)(ws + FIXED + FULLSCR);   // [2][3][1536]

    char* SCR = ws + FIXED;

    biascat_kernel<<<dim3(24), dim3(256), 0, stream>>>(bq, bk, bv, bqkv);
    transpose_cast<<<dim3(16,16,4), dim3(256), 0, stream>>>(Wq, WTqkv,          512, 512, 262144, 786432);
    transpose_cast<<<dim3(16,16,4), dim3(256), 0, stream>>>(Wk, WTqkv + 262144, 512, 512, 262144, 786432);
    transpose_cast<<<dim3(16,16,4), dim3(256), 0, stream>>>(Wv, WTqkv + 524288, 512, 512, 262144, 786432);
    transpose_cast<<<dim3(16,16,4), dim3(256), 0, stream>>>(W1, WT1, 512, 512, 262144, 262144);
    transpose_cast<<<dim3(16,16,4), dim3(256), 0, stream>>>(W2, WT2, 512, 512, 262144, 262144);
    transpose_cast<<<dim3(16,32,1), dim3(256), 0, stream>>>(pW1, pW1T, 1024, 512, 0, 0);
    transpose_cast<<<dim3(16,16,1), dim3(256), 0, stream>>>(pW1, pW1aT, 512, 512, 0, 0);
    transpose_cast<<<dim3(16,16,1), dim3(256), 0, stream>>>(pW1 + 262144, pW1bT, 512, 512, 0, 0);
    transpose_cast<<<dim3(8,16,1),  dim3(256), 0, stream>>>(pW2, pW2T, 512, 256, 0, 0);
    embed_kernel<<<dim3(3200), dim3(256), 0, stream>>>(probs_his, knows_his, corrs,
        knows_tab, probs_tab, types_tab, pos_tab, info, X);
    if (full)
        tproj_kernel<<<dim3(36), dim3(256), 0, stream>>>(types_tab, WTqkv, Tt);

    const int BIG = 1 << 30;

    if (full) {
        bf* QKVc = (bf*)SCR;                           // [38400][1536]
        bf* Oc   = (bf*)(SCR + (size_t)38400 * 3072);  // [38400][512]
        bf* F1c  = (bf*)SCR;                           // [76800][512]
        bf* F2c  = (bf*)(SCR + (size_t)76800 * 1024);  // [76800][512]
        bf* Hin  = (bf*)SCR;                           // [38400][512]
        bf* h1c  = (bf*)(SCR + 39321600);              // [38400][512]
        bf* h2c  = (bf*)(SCR + 78643200);              // [38400][256]
        bf* IPb  = (bf*)(SCR + 98304000);              // [12800][512]

        for (int i = 0; i < 2; ++i) {
            for (int hlf = 0; hlf < 2; ++hlf) {
                int lidx = i + 2 * hlf;
                bf* Xh = X + (size_t)hlf * 38400 * DD;
                const bf* WTq = WTqkv + (size_t)lidx * 786432;
                if (i == 0) {
                    // base projection of info only; T-add folded into attention
                    gemm8<0><<<dim3(300), dim3(512), 0, stream>>>(
                        info, WTq, WTq, bqkv + lidx * 1536, bqkv + lidx * 1536,
                        QKVc, 1536, 512, 6, BIG);
                    attn_mfma<1><<<dim3(3072), dim3(128), 0, stream>>>(
                        QKVc, probs_his, Oc, hlf * 768, Tt + hlf * 4608, corrs);
                } else {
                    gemm8<0><<<dim3(900), dim3(512), 0, stream>>>(
                        Xh, WTq, WTq, bqkv + lidx * 1536, bqkv + lidx * 1536,
                        QKVc, 1536, 512, 6, BIG);
                    attn_mfma<0><<<dim3(3072), dim3(128), 0, stream>>>(
                        QKVc, probs_his, Oc, hlf * 768, nullptr, nullptr);
                }
                ln_kernel<<<dim3(9600), dim3(256), 0, stream>>>(
                    Xh, Oc, g1, be1, lidx, lidx);
            }
            // FFN combined f+b (M=76800) via gemm8
            gemm8<1><<<dim3(600), dim3(512), 0, stream>>>(
                X, WT1 + (size_t)i * 262144, WT1 + (size_t)(i + 2) * 262144,
                b1 + i * 512, b1 + (i + 2) * 512, F1c, 512, 512, 2, 150);
            gemm8<0><<<dim3(600), dim3(512), 0, stream>>>(
                F1c, WT2 + (size_t)i * 262144, WT2 + (size_t)(i + 2) * 262144,
                b2 + i * 512, b2 + (i + 2) * 512, F2c, 512, 512, 2, 150);
            ln_kernel<<<dim3(19200), dim3(256), 0, stream>>>(
                X, F2c, g2, be2, i, i + 2);
        }

        // head
        combine_kernel<<<dim3(9600), dim3(256), 0, stream>>>(X, info, Hin, 0, 512, 0);
        gemm_bt<0><<<dim3(400), dim3(256), 0, stream>>>(
            info, pW1bT, pW1bT, pb1, pb1, IPb, 512, 512, 4, BIG);
        gemm_head<<<dim3(1200), dim3(256), 0, stream>>>(Hin, pW1aT, IPb, h1c, 4);
        gemm_bt<1><<<dim3(600), dim3(256), 0, stream>>>(
            h1c, pW2T, pW2T, pb2, pb2, h2c, 256, 512, 2, BIG);
        head_final<<<dim3(9600), dim3(256), 0, stream>>>(
            h2c, pW3, pb3, probs_his, (float*)d_out, 0);
        return;
    }

    // ---------------- fallback: chunked path --------------
    bf* QKVc = (bf*)SCR;
    bf* Oc   = (bf*)(SCR + (size_t)CR * 3072);
    bf* F1c  = (bf*)SCR;
    bf* F2c  = (bf*)(SCR + (size_t)CR * 1024);
    bf* Hinc = (bf*)SCR;
    bf* h1c  = (bf*)(SCR + (size_t)CR * 2048);
    bf* h2c  = (bf*)(SCR + (size_t)CR * 3072);

    const int nck = 38400 / CR;
    const int MT = CR / 128;
    for (int i = 0; i < 2; ++i) {
        for (int hlf = 0; hlf < 2; ++hlf) {
            int lidx = i + 2 * hlf;
            const bf* WTq  = WTqkv + (size_t)lidx * 786432;
            const bf* WT1l = WT1   + (size_t)lidx * 262144;
            const bf* WT2l = WT2   + (size_t)lidx * 262144;
            for (int c = 0; c < nck; ++c) {
                int r0 = hlf * 38400 + c * CR;
                gemm_bt<0><<<dim3(MT * 12), dim3(256), 0, stream>>>(
                    X + (size_t)r0 * DD, WTq, WTq, bqkv + lidx * 1536,
                    bqkv + lidx * 1536, QKVc, 1536, 512, 12, BIG);
                attn_mfma<0><<<dim3((CR/50) * 4), dim3(128), 0, stream>>>(
                    QKVc, probs_his, Oc, r0 / 50, nullptr, nullptr);
                ln_kernel<<<dim3(CR/4), dim3(256), 0, stream>>>(
                    X + (size_t)r0 * DD, Oc, g1, be1, lidx, lidx);
            }
            for (int c = 0; c < nck; ++c) {
                int r0 = hlf * 38400 + c * CR;
                gemm_bt<1><<<dim3(MT * 4), dim3(256), 0, stream>>>(
                    X + (size_t)r0 * DD, WT1l, WT1l, b1 + lidx * 512,
                    b1 + lidx * 512, F1c, 512, 512, 4, BIG);
                gemm_bt<0><<<dim3(MT * 4), dim3(256), 0, stream>>>(
                    F1c, WT2l, WT2l, b2 + lidx * 512, b2 + lidx * 512,
                    F2c, 512, 512, 4, BIG);
                ln_kernel<<<dim3(CR/4), dim3(256), 0, stream>>>(
                    X + (size_t)r0 * DD, F2c, g2, be2, lidx, lidx);
            }
        }
    }
    for (int c = 0; c < nck; ++c) {
        int rh0 = c * CR;
        combine_kernel<<<dim3(CR/4), dim3(256), 0, stream>>>(X, info, Hinc, rh0, 1024, 1);
        gemm_bt<1><<<dim3(MT * 4), dim3(256), 0, stream>>>(
            Hinc, pW1T, pW1T, pb1, pb1, h1c, 512, 1024, 4, BIG);
        gemm_bt<1><<<dim3(MT * 2), dim3(256), 0, stream>>>(
            h1c, pW2T, pW2T, pb2, pb2, h2c, 256, 512, 2, BIG);
        head_final<<<dim3(CR/4), dim3(256), 0, stream>>>(
            h2c, pW3, pb3, probs_his, (float*)d_out, rh0);
    }
}

// Round 12
// 1083.774 us; speedup vs baseline: 1.0912x; 1.0912x over previous
//
#include <hip/hip_runtime.h>
#include <hip/hip_bf16.h>

// Problem constants
#define SEQ 50
#define DD  512
#define NHD 8
#define HDIM 64
#define MPROWS 38400   // 3*256*50  (rows per stream half)
#define MTROWS 76800   // 2*MPROWS

typedef __hip_bfloat16 bf;
typedef __attribute__((ext_vector_type(8))) short bf16x8;
typedef __attribute__((ext_vector_type(4))) float f32x4;

__device__ __forceinline__ float bf2f(unsigned short u) {
    unsigned int x = ((unsigned int)u) << 16;
    return __builtin_bit_cast(float, x);
}
__device__ __forceinline__ unsigned short f2bu(float f) {
    unsigned int u = __builtin_bit_cast(unsigned int, f);
    u += 0x7fffu + ((u >> 16) & 1u);
    return (unsigned short)(u >> 16);
}

#define ASYNC16(g, l) __builtin_amdgcn_global_load_lds( \
    (__attribute__((address_space(1))) void*)(g),       \
    (__attribute__((address_space(3))) void*)(l), 16, 0, 0)

// ---------------------------------------------------------------------------
__global__ __launch_bounds__(256) void transpose_cast(
    const float* __restrict__ src, bf* __restrict__ dst,
    int R, int C, size_t sStride, size_t dStride)
{
    __shared__ float tile[32][33];
    int l = blockIdx.z;
    src += (size_t)l * sStride;
    dst += (size_t)l * dStride;
    int c0 = blockIdx.x * 32, r0 = blockIdx.y * 32;
    int tx = threadIdx.x & 31, ty = threadIdx.x >> 5;
    for (int i = ty; i < 32; i += 8)
        tile[i][tx] = src[(size_t)(r0 + i) * C + c0 + tx];
    __syncthreads();
    for (int i = ty; i < 32; i += 8)
        dst[(size_t)(c0 + i) * R + r0 + tx] = __float2bfloat16(tile[tx][i]);
}

__global__ __launch_bounds__(256) void biascat_kernel(
    const float* __restrict__ bq, const float* __restrict__ bk,
    const float* __restrict__ bv, float* __restrict__ out)
{
    int i = blockIdx.x * 256 + threadIdx.x;
    if (i >= 4 * 1536) return;
    int l = i / 1536, c = i % 1536;
    float v;
    if (c < 512)       v = bq[l * 512 + c];
    else if (c < 1024) v = bk[l * 512 + c - 512];
    else               v = bv[l * 512 + c - 1024];
    out[i] = v;
}

__global__ __launch_bounds__(256) void tproj_kernel(
    const float* __restrict__ types_tab, const bf* __restrict__ WTqkv,
    bf* __restrict__ Tt)
{
    int gid = blockIdx.x * 256 + threadIdx.x;
    if (gid >= 9216) return;
    int hl = gid / 4608;
    int t  = (gid / 1536) % 3;
    int n  = gid % 1536;
    const unsigned short* w =
        (const unsigned short*)(WTqkv + (size_t)(hl * 2) * 786432 + (size_t)n * 512);
    const float* ty = types_tab + t * 512;
    float a = 0.f;
    for (int k = 0; k < 512; ++k) a += ty[k] * bf2f(w[k]);
    Tt[gid] = __float2bfloat16(a);
}

// ---------------------------------------------------------------------------
__global__ __launch_bounds__(256) void embed_kernel(
    const int* __restrict__ probs_his, const int* __restrict__ knows_his,
    const int* __restrict__ corrs, const float* __restrict__ knows_tab,
    const float* __restrict__ probs_tab, const float* __restrict__ types_tab,
    const float* __restrict__ pos_tab, bf* __restrict__ info, bf* __restrict__ X)
{
    int bs = blockIdx.x * 4 + (threadIdx.x >> 6);
    int lane = threadIdx.x & 63;
    int s = bs % SEQ;
    int p = probs_his[bs];
    int c = corrs[bs];
    int d0 = lane * 8;

    float v[8];
    #pragma unroll
    for (int j = 0; j < 8; ++j)
        v[j] = probs_tab[(size_t)p * DD + d0 + j] + pos_tab[(size_t)s * DD + d0 + j];
    for (int k = 0; k < 8; ++k) {
        int ki = knows_his[bs * 8 + k];
        const float* kr = knows_tab + (size_t)ki * DD + d0;
        #pragma unroll
        for (int j = 0; j < 8; ++j) v[j] += kr[j];
    }
    int t0 = c ? 1 : 2;
    int t1 = c ? 2 : 0;
    int t2 = c ? 1 : 0;
    const float* T0 = types_tab + t0 * DD + d0;
    const float* T1 = types_tab + t1 * DD + d0;
    const float* T2 = types_tab + t2 * DD + d0;
    uint4 xi, x0, x1, x2;
    unsigned short* pi = (unsigned short*)&xi;
    unsigned short* p0 = (unsigned short*)&x0;
    unsigned short* p1 = (unsigned short*)&x1;
    unsigned short* p2 = (unsigned short*)&x2;
    #pragma unroll
    for (int j = 0; j < 8; ++j) {
        pi[j] = f2bu(v[j]);
        p0[j] = f2bu(v[j] + T0[j]);
        p1[j] = f2bu(v[j] + T1[j]);
        p2[j] = f2bu(v[j] + T2[j]);
    }
    size_t base = (size_t)bs * DD + d0;
    const size_t PB = (size_t)12800 * DD;
    *(uint4*)(info + base) = xi;
    *(uint4*)(X + 0 * PB + base) = x0;
    *(uint4*)(X + 1 * PB + base) = x1;
    *(uint4*)(X + 2 * PB + base) = x2;
    *(uint4*)(X + 3 * PB + base) = x0;
    *(uint4*)(X + 4 * PB + base) = x1;
    *(uint4*)(X + 5 * PB + base) = x2;
}

// ---------------------------------------------------------------------------
// GEMM 128x128 (proven core, round-7 scalar epilogue).
template <int RELU>
__global__ __launch_bounds__(256) void gemm_bt(
    const bf* __restrict__ Ap, const bf* __restrict__ WT0, const bf* __restrict__ WT1,
    const float* __restrict__ bias0, const float* __restrict__ bias1,
    bf* __restrict__ Cp, int N, int Kd, int nN, int mtHalf)
{
    __shared__ bf Al[128 * 64];
    __shared__ bf Bl[128 * 64];
    int nwg = gridDim.x;
    int f = blockIdx.x;
    int q8 = nwg >> 3, r8 = nwg & 7;
    int xcd = f & 7, pos = f >> 3;
    int e = (xcd < r8 ? xcd * (q8 + 1) : r8 * (q8 + 1) + (xcd - r8) * q8) + pos;
    int bm = e / nN, bn = e - bm * nN;
    const bf* WTp;
    const float* bias;
    if (bm < mtHalf) { WTp = WT0; bias = bias0; }
    else             { WTp = WT1; bias = bias1; }
    int m0 = bm * 128, n0 = bn * 128;
    int t = threadIdx.x, lane = t & 63, wave = t >> 6;
    int wr = wave >> 1, wc = wave & 1;
    int lr = lane & 15, lg = lane >> 4;

    f32x4 acc[4][4];
    #pragma unroll
    for (int m = 0; m < 4; ++m)
        #pragma unroll
        for (int n = 0; n < 4; ++n)
            acc[m][n] = (f32x4){0.f, 0.f, 0.f, 0.f};

    for (int kt = 0; kt < Kd; kt += 64) {
        #pragma unroll
        for (int i = 0; i < 4; ++i) {
            int c = i * 256 + t;
            int row = c >> 3, col = (c & 7) * 8;
            ASYNC16(Ap  + (size_t)(m0 + row) * Kd + kt + col, Al + c * 8);
            ASYNC16(WTp + (size_t)(n0 + row) * Kd + kt + col, Bl + c * 8);
        }
        __syncthreads();
        #pragma unroll
        for (int kk = 0; kk < 64; kk += 32) {
            int ko = kk + lg * 8;
            bf16x8 af[4], bfr[4];
            #pragma unroll
            for (int m = 0; m < 4; ++m)
                af[m] = *(const bf16x8*)(Al + (wr * 64 + m * 16 + lr) * 64 + ko);
            #pragma unroll
            for (int n = 0; n < 4; ++n)
                bfr[n] = *(const bf16x8*)(Bl + (wc * 64 + n * 16 + lr) * 64 + ko);
            #pragma unroll
            for (int m = 0; m < 4; ++m)
                #pragma unroll
                for (int n = 0; n < 4; ++n)
                    acc[m][n] = __builtin_amdgcn_mfma_f32_16x16x32_bf16(af[m], bfr[n], acc[m][n], 0, 0, 0);
        }
        __syncthreads();
    }
    unsigned short* Cs = (unsigned short*)Cp;
    #pragma unroll
    for (int n = 0; n < 4; ++n) {
        int col = n0 + wc * 64 + n * 16 + lr;
        float bvv = bias[col];
        #pragma unroll
        for (int m = 0; m < 4; ++m) {
            #pragma unroll
            for (int r = 0; r < 4; ++r) {
                int row = m0 + wr * 64 + m * 16 + lg * 4 + r;
                float v = acc[m][n][r] + bvv;
                if (RELU) v = fmaxf(v, 0.f);
                Cs[(size_t)row * N + col] = f2bu(v);
            }
        }
    }
}

// ---------------------------------------------------------------------------
// 256x256 8-phase GEMM — EXACT round-10 version (scalar epilogue, 99us QKV).
template <int RELU>
__global__ __launch_bounds__(512, 2) void gemm8(
    const bf* __restrict__ Ap, const bf* __restrict__ WTp,
    const float* __restrict__ bias, bf* __restrict__ Cp,
    int N, int Kd, int nN)
{
    __shared__ __align__(16) bf As[2][16384];
    __shared__ __align__(16) bf Bs[2][16384];

    int nwg = gridDim.x, f = blockIdx.x;
    int q8 = nwg >> 3, r8 = nwg & 7;
    int xcd = f & 7, pos = f >> 3;
    int e = (xcd < r8 ? xcd * (q8 + 1) : r8 * (q8 + 1) + (xcd - r8) * q8) + pos;
    int bm = e / nN, bn = e - bm * nN;
    int m0 = bm * 256, n0 = bn * 256;
    int t = threadIdx.x, lane = t & 63, wave = t >> 6;
    int wm = wave >> 2, wn = wave & 3;
    int lr = lane & 15, kg = lane >> 4;

    int srow = t >> 3;          // 0..63 (row within 64-row load group)
    int scolb = (t & 7) * 16;   // dest col byte (linear)
    const bf* Abase = Ap + (size_t)m0 * Kd;
    const bf* Bbase = WTp + (size_t)n0 * Kd;

#define STG(dsts, base, half, kt) do {                                        \
    _Pragma("unroll")                                                         \
    for (int _i = 0; _i < 2; ++_i) {                                          \
        int _r = (half) * 128 + _i * 64 + srow;                               \
        ASYNC16((base) + (size_t)_r * Kd + (kt) +                             \
                    ((scolb ^ ((_r & 7) << 4)) >> 1),                         \
                (dsts) + _r * 64 + (t & 7) * 8);                              \
    } } while (0)

    f32x4 acc[8][4];
    #pragma unroll
    for (int m = 0; m < 8; ++m)
        #pragma unroll
        for (int n = 0; n < 4; ++n)
            acc[m][n] = (f32x4){0.f, 0.f, 0.f, 0.f};

    STG(As[0], Abase, 0, 0);
    STG(As[0], Abase, 1, 0);
    STG(Bs[0], Bbase, 0, 0);
    STG(Bs[0], Bbase, 1, 0);

    int ntile = Kd >> 6;
    bf16x8 breg[4][2];
    for (int j = 0; j < ntile; ++j) {
        int d = j & 1;
        const char* Ab = (const char*)As[d];
        const char* Bb = (const char*)Bs[d];
        asm volatile("s_waitcnt vmcnt(0)" ::: "memory");
        __builtin_amdgcn_s_barrier();
        int kt1 = (j + 1) << 6;
        int pf = (j + 1 < ntile);
        #pragma unroll
        for (int q = 0; q < 4; ++q) {
            if (q == 0) {
                #pragma unroll
                for (int ns = 0; ns < 4; ++ns) {
                    int row = wn * 64 + ns * 16 + lr;
                    int sw = (row & 7) << 4;
                    breg[ns][0] = *(const bf16x8*)(Bb + row * 128 + ((kg * 16) ^ sw));
                    breg[ns][1] = *(const bf16x8*)(Bb + row * 128 + ((64 + kg * 16) ^ sw));
                }
            }
            bf16x8 areg[2][2];
            #pragma unroll
            for (int mm = 0; mm < 2; ++mm) {
                int row = wm * 128 + (2 * q + mm) * 16 + lr;
                int sw = (row & 7) << 4;
                areg[mm][0] = *(const bf16x8*)(Ab + row * 128 + ((kg * 16) ^ sw));
                areg[mm][1] = *(const bf16x8*)(Ab + row * 128 + ((64 + kg * 16) ^ sw));
            }
            if (pf) {
                if (q == 0)      STG(As[d ^ 1], Abase, 0, kt1);
                else if (q == 1) STG(As[d ^ 1], Abase, 1, kt1);
                else if (q == 2) STG(Bs[d ^ 1], Bbase, 0, kt1);
                else             STG(Bs[d ^ 1], Bbase, 1, kt1);
            }
            __builtin_amdgcn_s_barrier();
            __builtin_amdgcn_s_setprio(1);
            #pragma unroll
            for (int mm = 0; mm < 2; ++mm)
                #pragma unroll
                for (int ns = 0; ns < 4; ++ns) {
                    acc[2 * q + mm][ns] = __builtin_amdgcn_mfma_f32_16x16x32_bf16(
                        areg[mm][0], breg[ns][0], acc[2 * q + mm][ns], 0, 0, 0);
                    acc[2 * q + mm][ns] = __builtin_amdgcn_mfma_f32_16x16x32_bf16(
                        areg[mm][1], breg[ns][1], acc[2 * q + mm][ns], 0, 0, 0);
                }
            __builtin_amdgcn_s_setprio(0);
            if (q != 3) __builtin_amdgcn_s_barrier();
        }
    }
#undef STG

    unsigned short* Cs = (unsigned short*)Cp;
    #pragma unroll
    for (int ns = 0; ns < 4; ++ns) {
        int col = n0 + wn * 64 + ns * 16 + lr;
        float bvv = bias[col];
        #pragma unroll
        for (int ms = 0; ms < 8; ++ms) {
            #pragma unroll
            for (int rr = 0; rr < 4; ++rr) {
                int row = m0 + wm * 128 + ms * 16 + kg * 4 + rr;
                float v = acc[ms][ns][rr] + bvv;
                if (RELU) v = fmaxf(v, 0.f);
                Cs[(size_t)row * N + col] = f2bu(v);
            }
        }
    }
}

// ---------------------------------------------------------------------------
// Head GEMM (round-7 proven): h1 = relu(Hin @ pW1a + IP[row%12800]).
__global__ __launch_bounds__(256) void gemm_head(
    const bf* __restrict__ Ap, const bf* __restrict__ WTp,
    const bf* __restrict__ IPp, bf* __restrict__ Cp, int nN)
{
    __shared__ bf Al[128 * 64];
    __shared__ bf Bl[128 * 64];
    const int Kd = 512, N = 512;
    int nwg = gridDim.x;
    int f = blockIdx.x;
    int q8 = nwg >> 3, r8 = nwg & 7;
    int xcd = f & 7, pos = f >> 3;
    int e = (xcd < r8 ? xcd * (q8 + 1) : r8 * (q8 + 1) + (xcd - r8) * q8) + pos;
    int bm = e / nN, bn = e - bm * nN;
    int m0 = bm * 128, n0 = bn * 128;
    int t = threadIdx.x, lane = t & 63, wave = t >> 6;
    int wr = wave >> 1, wc = wave & 1;
    int lr = lane & 15, lg = lane >> 4;

    f32x4 acc[4][4];
    #pragma unroll
    for (int m = 0; m < 4; ++m)
        #pragma unroll
        for (int n = 0; n < 4; ++n)
            acc[m][n] = (f32x4){0.f, 0.f, 0.f, 0.f};

    for (int kt = 0; kt < Kd; kt += 64) {
        #pragma unroll
        for (int i = 0; i < 4; ++i) {
            int c = i * 256 + t;
            int row = c >> 3, col = (c & 7) * 8;
            ASYNC16(Ap  + (size_t)(m0 + row) * Kd + kt + col, Al + c * 8);
            ASYNC16(WTp + (size_t)(n0 + row) * Kd + kt + col, Bl + c * 8);
        }
        __syncthreads();
        #pragma unroll
        for (int kk = 0; kk < 64; kk += 32) {
            int ko = kk + lg * 8;
            bf16x8 af[4], bfr[4];
            #pragma unroll
            for (int m = 0; m < 4; ++m)
                af[m] = *(const bf16x8*)(Al + (wr * 64 + m * 16 + lr) * 64 + ko);
            #pragma unroll
            for (int n = 0; n < 4; ++n)
                bfr[n] = *(const bf16x8*)(Bl + (wc * 64 + n * 16 + lr) * 64 + ko);
            #pragma unroll
            for (int m = 0; m < 4; ++m)
                #pragma unroll
                for (int n = 0; n < 4; ++n)
                    acc[m][n] = __builtin_amdgcn_mfma_f32_16x16x32_bf16(af[m], bfr[n], acc[m][n], 0, 0, 0);
        }
        __syncthreads();
    }
    unsigned short* Cs = (unsigned short*)Cp;
    const unsigned short* IPu = (const unsigned short*)IPp;
    #pragma unroll
    for (int n = 0; n < 4; ++n) {
        int col = n0 + wc * 64 + n * 16 + lr;
        #pragma unroll
        for (int m = 0; m < 4; ++m) {
            #pragma unroll
            for (int r = 0; r < 4; ++r) {
                int row = m0 + wr * 64 + m * 16 + lg * 4 + r;
                int rr = row % 12800;
                float v = acc[m][n][r] + bf2f(IPu[(size_t)rr * 512 + col]);
                v = fmaxf(v, 0.f);
                Cs[(size_t)row * N + col] = f2bu(v);
            }
        }
    }
}

// ---------------------------------------------------------------------------
// MFMA attention. One wave per (seq, head); 2 waves/block.
// L0=1: QKVc is the 12800-row base projection; per-row type projection
// Tsel[t(pass,corrs)] is added to Q/K fragments and V staging on the fly.
template <int L0>
__global__ __launch_bounds__(128, 2) void attn_mfma(
    const bf* __restrict__ QKVc, const int* __restrict__ probs_his,
    bf* __restrict__ Oc, int seq0,
    const bf* __restrict__ Tsel, const int* __restrict__ corrs)
{
    __shared__ bf Pl_s[2][4096];
    __shared__ bf Vt_s[2][4096];
    int wave = threadIdx.x >> 6, lane = threadIdx.x & 63;
    bf* Pl = Pl_s[wave];
    bf* Vt = Vt_s[wave];
    int task = blockIdx.x * 2 + wave;
    int h = task & 7, seqL = task >> 3;
    int seqG = seq0 + seqL;
    int st = seqG / 768, b = seqG % 256;
    int pass = (seqG % 768) / 256;       // 0=right,1=wrong,2=norm
    int lr = lane & 15, kg = lane >> 4;
    size_t qkrow = L0 ? (size_t)b * SEQ : (size_t)seqL * SEQ;
    const bf* Qb = QKVc + qkrow * 1536 + h * HDIM;
    const bf* Kb = Qb + 512;
    const bf* Vb = Qb + 1024;
    const unsigned short* Tu = (const unsigned short*)Tsel;

    int pvv = (lane < SEQ) ? probs_his[b * SEQ + lane] : 1;
    unsigned long long padm = __ballot(pvv == 0) | 0xFFFC000000000000ull;

    // ---- stage V transposed (swizzled); L0 adds Tv per key row
    #pragma unroll
    for (int it = 0; it < 8; ++it) {
        int idx = it * 64 + lane;
        int key = idx >> 3, d0 = (idx & 7) * 8;
        uint4 v4 = make_uint4(0u, 0u, 0u, 0u);
        if (key < SEQ) v4 = *(const uint4*)(Vb + (size_t)key * 1536 + d0);
        unsigned short* vs = (unsigned short*)&v4;
        if (L0) {
            int kk2 = (key < SEQ) ? key : (SEQ - 1);
            int cc = corrs[b * SEQ + kk2];
            int tt = (pass == 0) ? (cc ? 1 : 2) : (pass == 1) ? (cc ? 2 : 0) : (cc ? 1 : 0);
            const unsigned short* Tv = Tu + tt * 1536 + 1024 + h * HDIM + d0;
            #pragma unroll
            for (int j = 0; j < 8; ++j)
                vs[j] = f2bu(bf2f(vs[j]) + bf2f(Tv[j]));
        }
        #pragma unroll
        for (int j = 0; j < 8; ++j) {
            int d = d0 + j;
            int byt = (d * 128 + key * 2) ^ ((j & 7) << 4);
            *(unsigned short*)((char*)Vt + byt) = vs[j];
        }
    }

    // ---- S^T = K @ Q^T (L0 adds Tq/Tk per row)
    bf16x8 kf[4][2], qf[4][2];
    #pragma unroll
    for (int m = 0; m < 4; ++m) {
        int rk = 16 * m + lr; if (rk > SEQ - 1) rk = SEQ - 1;
        int tt = 0;
        if (L0) {
            int cc = corrs[b * SEQ + rk];
            tt = (pass == 0) ? (cc ? 1 : 2) : (pass == 1) ? (cc ? 2 : 0) : (cc ? 1 : 0);
        }
        #pragma unroll
        for (int kb = 0; kb < 2; ++kb) {
            kf[m][kb] = *(const bf16x8*)(Kb + (size_t)rk * 1536 + kb * 32 + kg * 8);
            qf[m][kb] = *(const bf16x8*)(Qb + (size_t)rk * 1536 + kb * 32 + kg * 8);
            if (L0) {
                const unsigned short* Tq = Tu + tt * 1536 + h * HDIM + kb * 32 + kg * 8;
                #pragma unroll
                for (int j = 0; j < 8; ++j) {
                    qf[m][kb][j] = (short)f2bu(bf2f((unsigned short)qf[m][kb][j]) + bf2f(Tq[j]));
                    kf[m][kb][j] = (short)f2bu(bf2f((unsigned short)kf[m][kb][j]) + bf2f(Tq[512 + j]));
                }
            }
        }
    }
    f32x4 sacc[4][4];
    #pragma unroll
    for (int m = 0; m < 4; ++m)
        #pragma unroll
        for (int n = 0; n < 4; ++n)
            sacc[m][n] = (f32x4){0.f, 0.f, 0.f, 0.f};
    #pragma unroll
    for (int kb = 0; kb < 2; ++kb)
        #pragma unroll
        for (int m = 0; m < 4; ++m)
            #pragma unroll
            for (int n = 0; n < 4; ++n)
                sacc[m][n] = __builtin_amdgcn_mfma_f32_16x16x32_bf16(kf[m][kb], qf[n][kb], sacc[m][n], 0, 0, 0);

    #pragma unroll
    for (int n = 0; n < 4; ++n) {
        int q = 16 * n + lr;
        int qpad = (int)((padm >> q) & 1ull);
        float p[4][4];
        float mx = -3e38f;
        #pragma unroll
        for (int m = 0; m < 4; ++m)
            #pragma unroll
            for (int r = 0; r < 4; ++r) {
                int key = 16 * m + 4 * kg + r;
                int blocked = qpad | (int)((padm >> key) & 1ull) |
                              (st == 0 ? (key > q) : (key < q));
                float s = sacc[m][n][r] * 0.125f;
                p[m][r] = blocked ? -3e38f : s;
                if (!blocked) mx = fmaxf(mx, s);
            }
        mx = fmaxf(mx, __shfl_xor(mx, 16));
        mx = fmaxf(mx, __shfl_xor(mx, 32));
        float sum = 0.f;
        #pragma unroll
        for (int m = 0; m < 4; ++m)
            #pragma unroll
            for (int r = 0; r < 4; ++r) {
                float e = (p[m][r] > -1e37f) ? __expf(p[m][r] - mx) : 0.f;
                p[m][r] = e;
                sum += e;
            }
        sum += __shfl_xor(sum, 16);
        sum += __shfl_xor(sum, 32);
        float inv = (sum > 0.f) ? 1.f / sum : 0.f;
        #pragma unroll
        for (int m = 0; m < 4; ++m) {
            unsigned int u0 = (unsigned int)f2bu(p[m][0] * inv) |
                              ((unsigned int)f2bu(p[m][1] * inv) << 16);
            unsigned int u1 = (unsigned int)f2bu(p[m][2] * inv) |
                              ((unsigned int)f2bu(p[m][3] * inv) << 16);
            int base = (q * 128 + (16 * m + 4 * kg) * 2) ^ ((q & 7) << 4);
            *(unsigned int*)((char*)Pl + base) = u0;
            *(unsigned int*)((char*)Pl + base + 4) = u1;
        }
    }

    f32x4 oacc[4][4];
    #pragma unroll
    for (int m = 0; m < 4; ++m)
        #pragma unroll
        for (int n = 0; n < 4; ++n)
            oacc[m][n] = (f32x4){0.f, 0.f, 0.f, 0.f};
    #pragma unroll
    for (int kb = 0; kb < 2; ++kb) {
        bf16x8 vf[4], pf[4];
        #pragma unroll
        for (int m = 0; m < 4; ++m) {
            int row = 16 * m + lr;
            int byt = (row * 128 + (kb * 32 + kg * 8) * 2) ^ ((row & 7) << 4);
            vf[m] = *(const bf16x8*)((char*)Vt + byt);
            pf[m] = *(const bf16x8*)((char*)Pl + byt);
        }
        #pragma unroll
        for (int m = 0; m < 4; ++m)
            #pragma unroll
            for (int n = 0; n < 4; ++n)
                oacc[m][n] = __builtin_amdgcn_mfma_f32_16x16x32_bf16(vf[m], pf[n], oacc[m][n], 0, 0, 0);
    }
    #pragma unroll
    for (int n = 0; n < 4; ++n) {
        int q = 16 * n + lr;
        if (q < SEQ) {
            #pragma unroll
            for (int m = 0; m < 4; ++m) {
                uint2 ov;
                ov.x = (unsigned int)f2bu(oacc[m][n][0]) | ((unsigned int)f2bu(oacc[m][n][1]) << 16);
                ov.y = (unsigned int)f2bu(oacc[m][n][2]) | ((unsigned int)f2bu(oacc[m][n][3]) << 16);
                *(uint2*)(Oc + (size_t)(seqL * SEQ + q) * DD + h * HDIM + 16 * m + 4 * kg) = ov;
            }
        }
    }
}

// ---------------------------------------------------------------------------
__global__ __launch_bounds__(256) void ln_kernel(
    bf* __restrict__ X, const bf* __restrict__ Rb,
    const float* __restrict__ g_all, const float* __restrict__ be_all,
    int lf, int lb)
{
    int row = blockIdx.x * 4 + (threadIdx.x >> 6);
    int lane = threadIdx.x & 63;
    int layer = (row < MPROWS) ? lf : lb;
    const float* g = g_all + layer * DD;
    const float* be = be_all + layer * DD;
    uint4 xa = *((const uint4*)(X + (size_t)row * DD) + lane);
    uint4 ra = *((const uint4*)(Rb + (size_t)row * DD) + lane);
    unsigned short* xs = (unsigned short*)&xa;
    unsigned short* rs = (unsigned short*)&ra;
    float v[8];
    float sum = 0.f;
    #pragma unroll
    for (int j = 0; j < 8; ++j) { v[j] = bf2f(xs[j]) + bf2f(rs[j]); sum += v[j]; }
    #pragma unroll
    for (int o = 1; o < 64; o <<= 1) sum += __shfl_xor(sum, o);
    float mu = sum * (1.f / 512.f);
    float ss = 0.f;
    #pragma unroll
    for (int j = 0; j < 8; ++j) { float d = v[j] - mu; ss += d * d; }
    #pragma unroll
    for (int o = 1; o < 64; o <<= 1) ss += __shfl_xor(ss, o);
    float inv = rsqrtf(ss * (1.f / 512.f) + 1e-5f);
    int d0 = lane * 8;
    uint4 ov;
    unsigned short* os = (unsigned short*)&ov;
    #pragma unroll
    for (int j = 0; j < 8; ++j)
        os[j] = f2bu((v[j] - mu) * inv * g[d0 + j] + be[d0 + j]);
    *((uint4*)(X + (size_t)row * DD) + lane) = ov;
}

// ---------------------------------------------------------------------------
__global__ __launch_bounds__(256) void combine_kernel(
    const bf* __restrict__ X, const bf* __restrict__ info,
    bf* __restrict__ Hinc, int rh0, int hstride, int withInfo)
{
    int rl = blockIdx.x * 4 + (threadIdx.x >> 6);
    int rh = rh0 + rl;
    int lane = threadIdx.x & 63;
    int s = rh % SEQ, pb = rh / SEQ, b = pb & 255;
    const size_t MPD = (size_t)MPROWS * DD;
    uint4 o;
    if (s == 0) {
        o = *((const uint4*)(X + MPD + (size_t)(pb * SEQ) * DD) + lane);
    } else if (s == SEQ - 1) {
        o = *((const uint4*)(X + (size_t)(pb * SEQ + SEQ - 1) * DD) + lane);
    } else {
        uint4 a = *((const uint4*)(X + (size_t)(pb * SEQ + s - 1) * DD) + lane);
        uint4 c2 = *((const uint4*)(X + MPD + (size_t)(pb * SEQ + s + 1) * DD) + lane);
        unsigned short* as = (unsigned short*)&a;
        unsigned short* cs = (unsigned short*)&c2;
        unsigned short* os = (unsigned short*)&o;
        #pragma unroll
        for (int j = 0; j < 8; ++j) os[j] = f2bu(bf2f(as[j]) + bf2f(cs[j]));
    }
    *((uint4*)(Hinc + (size_t)rl * hstride) + lane) = o;
    if (withInfo) {
        uint4 iv = *((const uint4*)(info + (size_t)(b * SEQ + s) * DD) + lane);
        *((uint4*)(Hinc + (size_t)rl * hstride + 512) + lane) = iv;
    }
}

// ---------------------------------------------------------------------------
__global__ __launch_bounds__(256) void head_final(
    const bf* __restrict__ h2c, const float* __restrict__ pW3,
    const float* __restrict__ pb3, const int* __restrict__ probs_his,
    float* __restrict__ out, int rh0)
{
    int rl = blockIdx.x * 4 + (threadIdx.x >> 6);
    int row = rh0 + rl;
    int lane = threadIdx.x & 63;
    uint2 hv = *((const uint2*)(h2c + (size_t)rl * 256) + lane);
    unsigned short* hs = (unsigned short*)&hv;
    float s = 0.f;
    #pragma unroll
    for (int j = 0; j < 4; ++j) s += bf2f(hs[j]) * pW3[lane * 4 + j];
    #pragma unroll
    for (int o = 1; o < 64; o <<= 1) s += __shfl_xor(s, o);
    if (lane == 0) {
        float logit = s + pb3[0];
        float sc = 1.f / (1.f + __expf(-logit));
        int bb = (row / SEQ) & 255, ss2 = row % SEQ;
        out[row] = (probs_his[bb * SEQ + ss2] > 0) ? sc : 0.f;
    }
}

// ---------------------------------------------------------------------------
extern "C" void kernel_launch(void* const* d_in, const int* in_sizes, int n_in,
                              void* d_out, int out_size, void* d_ws, size_t ws_size,
                              hipStream_t stream) {
    const int*   probs_his = (const int*)d_in[0];
    const int*   knows_his = (const int*)d_in[1];
    const int*   corrs     = (const int*)d_in[2];
    const float* knows_tab = (const float*)d_in[3];
    const float* probs_tab = (const float*)d_in[4];
    const float* types_tab = (const float*)d_in[5];
    const float* pos_tab   = (const float*)d_in[6];
    const float* Wq = (const float*)d_in[7];
    const float* Wk = (const float*)d_in[8];
    const float* Wv = (const float*)d_in[9];
    const float* W1 = (const float*)d_in[10];
    const float* W2 = (const float*)d_in[11];
    const float* bq = (const float*)d_in[12];
    const float* bk = (const float*)d_in[13];
    const float* bv = (const float*)d_in[14];
    const float* b1 = (const float*)d_in[15];
    const float* b2 = (const float*)d_in[16];
    const float* be1 = (const float*)d_in[17];
    const float* be2 = (const float*)d_in[18];
    const float* g1 = (const float*)d_in[19];
    const float* g2 = (const float*)d_in[20];
    const float* pW1 = (const float*)d_in[21];
    const float* pb1 = (const float*)d_in[22];
    const float* pW2 = (const float*)d_in[23];
    const float* pb2 = (const float*)d_in[24];
    const float* pW3 = (const float*)d_in[25];
    const float* pb3 = (const float*)d_in[26];

    char* ws = (char*)d_ws;
    bf* WTqkv = (bf*)(ws + 0);              // [4][1536][512]
    bf* WT1   = (bf*)(ws + 6291456);        // [4][512][512]
    bf* WT2   = (bf*)(ws + 8388608);        // [4][512][512]
    bf* pW1T  = (bf*)(ws + 10485760);       // [512][1024]   (fallback)
    bf* pW1aT = (bf*)(ws + 11534336);       // [512][512]
    bf* pW1bT = (bf*)(ws + 12058624);       // [512][512]
    bf* pW2T  = (bf*)(ws + 12582912);       // [256][512]
    float* bqkv = (float*)(ws + 12845056);  // [4][1536]
    bf* info  = (bf*)(ws + 12869632);       // [12800][512]
    bf* X     = (bf*)(ws + 25976832);       // [76800][512]
    const size_t FIXED = 104620032ull;      // X end
    const size_t FULLSCR = (size_t)38400 * 4096;

    int CR;
    if      (ws_size >= FIXED + FULLSCR)                  CR = 38400;
    else if (ws_size >= FIXED + (size_t)19200 * 4096)     CR = 19200;
    else if (ws_size >= FIXED + (size_t)9600  * 4096)     CR = 9600;
    else                                                  CR = 3200;
    const int full = (CR == 38400) &&
        (ws_size >= FIXED + FULLSCR + 18432);
    bf* Tt = (bf*)(ws + FIXED + FULLSCR);   // [2][3][1536]

    char* SCR = ws + FIXED;

    biascat_kernel<<<dim3(24), dim3(256), 0, stream>>>(bq, bk, bv, bqkv);
    transpose_cast<<<dim3(16,16,4), dim3(256), 0, stream>>>(Wq, WTqkv,          512, 512, 262144, 786432);
    transpose_cast<<<dim3(16,16,4), dim3(256), 0, stream>>>(Wk, WTqkv + 262144, 512, 512, 262144, 786432);
    transpose_cast<<<dim3(16,16,4), dim3(256), 0, stream>>>(Wv, WTqkv + 524288, 512, 512, 262144, 786432);
    transpose_cast<<<dim3(16,16,4), dim3(256), 0, stream>>>(W1, WT1, 512, 512, 262144, 262144);
    transpose_cast<<<dim3(16,16,4), dim3(256), 0, stream>>>(W2, WT2, 512, 512, 262144, 262144);
    transpose_cast<<<dim3(16,32,1), dim3(256), 0, stream>>>(pW1, pW1T, 1024, 512, 0, 0);
    transpose_cast<<<dim3(16,16,1), dim3(256), 0, stream>>>(pW1, pW1aT, 512, 512, 0, 0);
    transpose_cast<<<dim3(16,16,1), dim3(256), 0, stream>>>(pW1 + 262144, pW1bT, 512, 512, 0, 0);
    transpose_cast<<<dim3(8,16,1),  dim3(256), 0, stream>>>(pW2, pW2T, 512, 256, 0, 0);
    embed_kernel<<<dim3(3200), dim3(256), 0, stream>>>(probs_his, knows_his, corrs,
        knows_tab, probs_tab, types_tab, pos_tab, info, X);
    if (full)
        tproj_kernel<<<dim3(36), dim3(256), 0, stream>>>(types_tab, WTqkv, Tt);

    const int BIG = 1 << 30;

    if (full) {
        bf* QKVc = (bf*)SCR;                           // [38400][1536]
        bf* Oc   = (bf*)(SCR + (size_t)38400 * 3072);  // [38400][512]
        bf* F1c  = (bf*)SCR;                           // [76800][512]
        bf* F2c  = (bf*)(SCR + (size_t)76800 * 1024);  // [76800][512]
        bf* Hin  = (bf*)SCR;                           // [38400][512]
        bf* h1c  = (bf*)(SCR + 39321600);              // [38400][512]
        bf* h2c  = (bf*)(SCR + 78643200);              // [38400][256]
        bf* IPb  = (bf*)(SCR + 98304000);              // [12800][512]

        for (int i = 0; i < 2; ++i) {
            for (int hlf = 0; hlf < 2; ++hlf) {
                int lidx = i + 2 * hlf;
                bf* Xh = X + (size_t)hlf * 38400 * DD;
                const bf* WTq = WTqkv + (size_t)lidx * 786432;
                if (i == 0) {
                    // base projection of info only; T-add folded into attention
                    gemm8<0><<<dim3(300), dim3(512), 0, stream>>>(
                        info, WTq, bqkv + lidx * 1536, QKVc, 1536, 512, 6);
                    attn_mfma<1><<<dim3(3072), dim3(128), 0, stream>>>(
                        QKVc, probs_his, Oc, hlf * 768, Tt + hlf * 4608, corrs);
                } else {
                    gemm8<0><<<dim3(900), dim3(512), 0, stream>>>(
                        Xh, WTq, bqkv + lidx * 1536, QKVc, 1536, 512, 6);
                    attn_mfma<0><<<dim3(3072), dim3(128), 0, stream>>>(
                        QKVc, probs_his, Oc, hlf * 768, nullptr, nullptr);
                }
                ln_kernel<<<dim3(9600), dim3(256), 0, stream>>>(
                    Xh, Oc, g1, be1, lidx, lidx);
            }
            // FFN combined f+b (M=76800) — round-10 gemm_bt path
            gemm_bt<1><<<dim3(2400), dim3(256), 0, stream>>>(
                X, WT1 + (size_t)i * 262144, WT1 + (size_t)(i + 2) * 262144,
                b1 + i * 512, b1 + (i + 2) * 512, F1c, 512, 512, 4, 300);
            gemm_bt<0><<<dim3(2400), dim3(256), 0, stream>>>(
                F1c, WT2 + (size_t)i * 262144, WT2 + (size_t)(i + 2) * 262144,
                b2 + i * 512, b2 + (i + 2) * 512, F2c, 512, 512, 4, 300);
            ln_kernel<<<dim3(19200), dim3(256), 0, stream>>>(
                X, F2c, g2, be2, i, i + 2);
        }

        // head
        combine_kernel<<<dim3(9600), dim3(256), 0, stream>>>(X, info, Hin, 0, 512, 0);
        gemm_bt<0><<<dim3(400), dim3(256), 0, stream>>>(
            info, pW1bT, pW1bT, pb1, pb1, IPb, 512, 512, 4, BIG);
        gemm_head<<<dim3(1200), dim3(256), 0, stream>>>(Hin, pW1aT, IPb, h1c, 4);
        gemm_bt<1><<<dim3(600), dim3(256), 0, stream>>>(
            h1c, pW2T, pW2T, pb2, pb2, h2c, 256, 512, 2, BIG);
        head_final<<<dim3(9600), dim3(256), 0, stream>>>(
            h2c, pW3, pb3, probs_his, (float*)d_out, 0);
        return;
    }

    // ---------------- fallback: chunked path --------------
    bf* QKVc = (bf*)SCR;
    bf* Oc   = (bf*)(SCR + (size_t)CR * 3072);
    bf* F1c  = (bf*)SCR;
    bf* F2c  = (bf*)(SCR + (size_t)CR * 1024);
    bf* Hinc = (bf*)SCR;
    bf* h1c  = (bf*)(SCR + (size_t)CR * 2048);
    bf* h2c  = (bf*)(SCR + (size_t)CR * 3072);

    const int nck = 38400 / CR;
    const int MT = CR / 128;
    for (int i = 0; i < 2; ++i) {
        for (int hlf = 0; hlf < 2; ++hlf) {
            int lidx = i + 2 * hlf;
            const bf* WTq  = WTqkv + (size_t)lidx * 786432;
            const bf* WT1l = WT1   + (size_t)lidx * 262144;
            const bf* WT2l = WT2   + (size_t)lidx * 262144;
            for (int c = 0; c < nck; ++c) {
                int r0 = hlf * 38400 + c * CR;
                gemm_bt<0><<<dim3(MT * 12), dim3(256), 0, stream>>>(
                    X + (size_t)r0 * DD, WTq, WTq, bqkv + lidx * 1536,
                    bqkv + lidx * 1536, QKVc, 1536, 512, 12, BIG);
                attn_mfma<0><<<dim3((CR/50) * 4), dim3(128), 0, stream>>>(
                    QKVc, probs_his, Oc, r0 / 50, nullptr, nullptr);
                ln_kernel<<<dim3(CR/4), dim3(256), 0, stream>>>(
                    X + (size_t)r0 * DD, Oc, g1, be1, lidx, lidx);
            }
            for (int c = 0; c < nck; ++c) {
                int r0 = hlf * 38400 + c * CR;
                gemm_bt<1><<<dim3(MT * 4), dim3(256), 0, stream>>>(
                    X + (size_t)r0 * DD, WT1l, WT1l, b1 + lidx * 512,
                    b1 + lidx * 512, F1c, 512, 512, 4, BIG);
                gemm_bt<0><<<dim3(MT * 4), dim3(256), 0, stream>>>(
                    F1c, WT2l, WT2l, b2 + lidx * 512, b2 + lidx * 512,
                    F2c, 512, 512, 4, BIG);
                ln_kernel<<<dim3(CR/4), dim3(256), 0, stream>>>(
                    X + (size_t)r0 * DD, F2c, g2, be2, lidx, lidx);
            }
        }
    }
    for (int c = 0; c < nck; ++c) {
        int rh0 = c * CR;
        combine_kernel<<<dim3(CR/4), dim3(256), 0, stream>>>(X, info, Hinc, rh0, 1024, 1);
        gemm_bt<1><<<dim3(MT * 4), dim3(256), 0, stream>>>(
            Hinc, pW1T, pW1T, pb1, pb1, h1c, 512, 1024, 4, BIG);
        gemm_bt<1><<<dim3(MT * 2), dim3(256), 0, stream>>>(
            h1c, pW2T, pW2T, pb2, pb2, h2c, 256, 512, 2, BIG);
        head_final<<<dim3(CR/4), dim3(256), 0, stream>>>(
            h2c, pW3, pb3, probs_his, (float*)d_out, rh0);
    }
}